// Round 1
// baseline (8054.845 us; speedup 1.0000x reference)
//
#include <hip/hip_runtime.h>
#include <hip/hip_bf16.h>

using bf16 = __hip_bfloat16;
typedef __attribute__((ext_vector_type(8))) short short8;
typedef __attribute__((ext_vector_type(4))) float f32x4;

static __device__ __forceinline__ float b2f(short s) {
    unsigned u = ((unsigned)(unsigned short)s) << 16;
    return __builtin_bit_cast(float, u);
}
static __device__ __forceinline__ short f2b(float f) {
    __hip_bfloat16 h = __float2bfloat16(f);
    return __builtin_bit_cast(short, h);
}

// ---------------- f32 -> bf16 conversion (8 elems/thread) ----------------
__global__ void f32_to_bf16_vec(const float* __restrict__ in, bf16* __restrict__ out, int n8) {
    int i = blockIdx.x * blockDim.x + threadIdx.x;
    if (i >= n8) return;
    const f32x4* p = (const f32x4*)(in + (size_t)i * 8);
    f32x4 a = p[0], b = p[1];
    short8 o;
    o[0] = f2b(a[0]); o[1] = f2b(a[1]); o[2] = f2b(a[2]); o[3] = f2b(a[3]);
    o[4] = f2b(b[0]); o[5] = f2b(b[1]); o[6] = f2b(b[2]); o[7] = f2b(b[3]);
    *(short8*)(out + (size_t)i * 8) = o;
}

// ---------------- GEMM: C = act(X @ W^T + bias), bf16 in/out ----------------
// X: [M, K] bf16, W: [Nout, K] bf16, C: [M, Nout] bf16
// 128x128 tile, BK=32, 256 threads (4 waves, 2x2), each wave 4x4 16x16 MFMA tiles.
template<int K, bool RELU>
__global__ __launch_bounds__(256) void gemm_xwt(
    const bf16* __restrict__ X, const bf16* __restrict__ W,
    const float* __restrict__ bias, bf16* __restrict__ C, int Nout)
{
    __shared__ bf16 As[128][40];  // row stride 80B (16B-aligned, 2-way bank)
    __shared__ bf16 Bs[128][40];
    const int tid  = threadIdx.x;
    const int wave = tid >> 6, lane = tid & 63;
    const int wr = wave >> 1, wc = wave & 1;
    const long Mbase = (long)blockIdx.x * 128;
    const int  Nbase = blockIdx.y * 128;
    const int kg = (lane >> 4) * 8;

    f32x4 acc[4][4];
#pragma unroll
    for (int i = 0; i < 4; ++i)
#pragma unroll
        for (int j = 0; j < 4; ++j) acc[i][j] = (f32x4){0.f, 0.f, 0.f, 0.f};

    for (int kb = 0; kb < K / 32; ++kb) {
        __syncthreads();
#pragma unroll
        for (int q = 0; q < 2; ++q) {
            int idx = q * 256 + tid;
            int row = idx >> 2, kp = (idx & 3) * 8;
            *(short8*)&As[row][kp] = *(const short8*)&X[(Mbase + row) * K + kb * 32 + kp];
            *(short8*)&Bs[row][kp] = *(const short8*)&W[(long)(Nbase + row) * K + kb * 32 + kp];
        }
        __syncthreads();
        short8 a[4], b[4];
#pragma unroll
        for (int mt = 0; mt < 4; ++mt)
            a[mt] = *(const short8*)&As[wr * 64 + mt * 16 + (lane & 15)][kg];
#pragma unroll
        for (int nt = 0; nt < 4; ++nt)
            b[nt] = *(const short8*)&Bs[wc * 64 + nt * 16 + (lane & 15)][kg];
#pragma unroll
        for (int mt = 0; mt < 4; ++mt)
#pragma unroll
            for (int nt = 0; nt < 4; ++nt)
                acc[mt][nt] = __builtin_amdgcn_mfma_f32_16x16x32_bf16(a[mt], b[nt], acc[mt][nt], 0, 0, 0);
    }

    // epilogue: C/D layout col=lane&15, row=(lane>>4)*4+r
#pragma unroll
    for (int mt = 0; mt < 4; ++mt) {
        int row0 = wr * 64 + mt * 16 + (lane >> 4) * 4;
#pragma unroll
        for (int nt = 0; nt < 4; ++nt) {
            int col = Nbase + wc * 64 + nt * 16 + (lane & 15);
            float bv = bias[col];
#pragma unroll
            for (int r = 0; r < 4; ++r) {
                float v = acc[mt][nt][r] + bv;
                if (RELU) v = fmaxf(v, 0.f);
                C[(Mbase + row0 + r) * (long)Nout + col] = __float2bfloat16(v);
            }
        }
    }
}

// ---------------- LayerNorm over rows of 512, bf16 -> bf16 ----------------
__global__ __launch_bounds__(256) void ln_rows512(
    const bf16* __restrict__ in, bf16* __restrict__ out,
    const float* __restrict__ g, const float* __restrict__ be)
{
    const int lane = threadIdx.x & 63;
    const long row = (long)blockIdx.x * 4 + (threadIdx.x >> 6);
    const bf16* rp = in + row * 512;
    short8 v = *(const short8*)&rp[lane * 8];
    float x[8]; float s = 0.f, sq = 0.f;
#pragma unroll
    for (int j = 0; j < 8; ++j) { x[j] = b2f(v[j]); s += x[j]; sq += x[j] * x[j]; }
#pragma unroll
    for (int m = 1; m < 64; m <<= 1) { s += __shfl_xor(s, m); sq += __shfl_xor(sq, m); }
    float mu   = s * (1.f / 512.f);
    float var  = sq * (1.f / 512.f) - mu * mu;
    float rstd = rsqrtf(var + 1e-5f);
    short8 o;
#pragma unroll
    for (int j = 0; j < 8; ++j) {
        int c = lane * 8 + j;
        o[j] = f2b((x[j] - mu) * rstd * g[c] + be[c]);
    }
    *(short8*)(out + row * 512 + lane * 8) = o;
}

// ---------------- GRU scan: 32 blocks x 16 batch rows, T=128 internal ----------------
// gi: [T*512, 1536] bf16 (bih included). Whh: [1536, 512] bf16.
// h state: hf (f32 master) + hb (bf16 masked copy, MFMA A operand) in LDS.
// Wave w owns h-cols [64w, 64w+64): computes gh cols {c, c+512, c+1024} itself,
// so gates are fully in-register. Fused final LN -> out; hT written at end.
__global__ __launch_bounds__(512) void gru_scan(
    const bf16* __restrict__ gi, const float* __restrict__ on_reset,
    const float* __restrict__ hx, const bf16* __restrict__ Whh,
    const float* __restrict__ bhh, const float* __restrict__ gr,
    const float* __restrict__ br, float* __restrict__ out, float* __restrict__ hT)
{
    __shared__ bf16  hb[16][520];   // row stride 1040B (16B aligned)
    __shared__ float hf[16][512];
    __shared__ float mrow[16];
    const int tid  = threadIdx.x;
    const int wave = tid >> 6, lane = tid & 63;
    const int n0 = blockIdx.x * 16;
    const int prow = tid >> 5;          // 0..15 (p0 / LN mapping: 32 threads per row)
    const int pc0  = (tid & 31) * 16;
    const int colbase = wave * 64;
    const int lcol = lane & 15;
    const int kg   = lane >> 4;

    // init h from hx
#pragma unroll
    for (int c = 0; c < 16; c += 4)
        *(f32x4*)&hf[prow][pc0 + c] = *(const f32x4*)&hx[(n0 + prow) * 512 + pc0 + c];
    __syncthreads();

    for (int t = 0; t < 128; ++t) {
        const long tb = (long)t * 512;
        // p0: apply reset mask, produce bf16 copy for MFMA
        float m = on_reset[tb + n0 + prow];
        if ((tid & 31) == 0) mrow[prow] = m;
#pragma unroll
        for (int c = 0; c < 16; ++c)
            hb[prow][pc0 + c] = __float2bfloat16(hf[prow][pc0 + c] * m);
        __syncthreads();

        // p1: gh = (h*m) @ Whh^T for this wave's 12 gh col-tiles
        short8 af[16];
#pragma unroll
        for (int kc = 0; kc < 16; ++kc)
            af[kc] = *(const short8*)&hb[lcol][kc * 32 + kg * 8];

        f32x4 acc[3][4];
#pragma unroll
        for (int gp = 0; gp < 3; ++gp)
#pragma unroll
            for (int ht = 0; ht < 4; ++ht) acc[gp][ht] = (f32x4){0.f, 0.f, 0.f, 0.f};

#pragma unroll
        for (int gp = 0; gp < 3; ++gp) {
#pragma unroll
            for (int ht = 0; ht < 4; ++ht) {
                const bf16* wrow = Whh + (long)(gp * 512 + colbase + ht * 16 + lcol) * 512;
#pragma unroll
                for (int kc = 0; kc < 16; ++kc) {
                    short8 bf_ = *(const short8*)&wrow[kc * 32 + kg * 8];
                    acc[gp][ht] = __builtin_amdgcn_mfma_f32_16x16x32_bf16(af[kc], bf_, acc[gp][ht], 0, 0, 0);
                }
            }
        }

        // gates (in-register; each lane owns rows kg*4+r, col colbase+ht*16+lcol)
#pragma unroll
        for (int ht = 0; ht < 4; ++ht) {
            int col = colbase + ht * 16 + lcol;
            float bhr = bhh[col], bhz = bhh[512 + col], bhn = bhh[1024 + col];
#pragma unroll
            for (int r = 0; r < 4; ++r) {
                int row = kg * 4 + r;
                const bf16* gp_ = gi + (tb + n0 + row) * 1536;
                float ir  = __bfloat162float(gp_[col]);
                float iz  = __bfloat162float(gp_[512 + col]);
                float inn = __bfloat162float(gp_[1024 + col]);
                float hr = acc[0][ht][r] + bhr;
                float hz = acc[1][ht][r] + bhz;
                float hn = acc[2][ht][r] + bhn;
                float rg = 1.f / (1.f + __expf(-(ir + hr)));
                float zg = 1.f / (1.f + __expf(-(iz + hz)));
                float ng = tanhf(inn + rg * hn);
                float hold = hf[row][col] * mrow[row];
                hf[row][col] = (1.f - zg) * ng + zg * hold;
            }
        }
        __syncthreads();

        // fused output LayerNorm of h_t -> out (f32)
        {
            float x[16]; float s = 0.f, sq = 0.f;
#pragma unroll
            for (int c = 0; c < 16; ++c) { x[c] = hf[prow][pc0 + c]; s += x[c]; sq += x[c] * x[c]; }
#pragma unroll
            for (int mm = 1; mm < 32; mm <<= 1) { s += __shfl_xor(s, mm); sq += __shfl_xor(sq, mm); }
            float mu   = s * (1.f / 512.f);
            float var  = sq * (1.f / 512.f) - mu * mu;
            float rstd = rsqrtf(var + 1e-5f);
            float* op = out + (tb + n0 + prow) * 512;
#pragma unroll
            for (int c = 0; c < 16; c += 4) {
                f32x4 o;
#pragma unroll
                for (int j = 0; j < 4; ++j)
                    o[j] = (x[c + j] - mu) * rstd * gr[pc0 + c + j] + br[pc0 + c + j];
                *(f32x4*)&op[pc0 + c] = o;
            }
        }
        __syncthreads();
    }

    // hT (post final update, no mask)
#pragma unroll
    for (int c = 0; c < 16; c += 4)
        *(f32x4*)&hT[(n0 + prow) * 512 + pc0 + c] = *(f32x4*)&hf[prow][pc0 + c];
}

// ---------------- launch ----------------
extern "C" void kernel_launch(void* const* d_in, const int* in_sizes, int n_in,
                              void* d_out, int out_size, void* d_ws, size_t ws_size,
                              hipStream_t stream) {
    const float* obs      = (const float*)d_in[0];   // [65536, 128]
    const float* hx       = (const float*)d_in[1];   // [512, 1, 512]
    const float* on_reset = (const float*)d_in[2];   // [65536, 1]
    const float* W1  = (const float*)d_in[3];
    const float* b1  = (const float*)d_in[4];
    const float* g1  = (const float*)d_in[5];
    const float* be1 = (const float*)d_in[6];
    const float* W2  = (const float*)d_in[7];
    const float* b2  = (const float*)d_in[8];
    const float* g2  = (const float*)d_in[9];
    const float* be2 = (const float*)d_in[10];
    const float* Wih = (const float*)d_in[11];
    const float* Whh = (const float*)d_in[12];
    const float* bih = (const float*)d_in[13];
    const float* bhh = (const float*)d_in[14];
    const float* gr  = (const float*)d_in[15];
    const float* br  = (const float*)d_in[16];

    // workspace layout (bytes)
    char* ws = (char*)d_ws;
    bf16* W1b  = (bf16*)(ws + 0);                    //   131072
    bf16* W2b  = (bf16*)(ws + 131072);               //   524288
    bf16* Wihb = (bf16*)(ws + 655360);               //  1572864
    bf16* Whhb = (bf16*)(ws + 2228224);              //  1572864
    bf16* Y    = (bf16*)(ws + 3801088);              // 67108864  (post-LN acts)
    bf16* GI   = (bf16*)(ws + 3801088 + 67108864);   // 201326592 (gi)
    bf16* X1   = GI;                                 // alias: raw (pre-LN) acts, dead before GI written
    bf16* OBSB = (bf16*)((char*)GI + 67108864);      // alias: obs bf16, dead before GI written
    // total required: 272,236,544 bytes

    // conversions
    f32_to_bf16_vec<<<(1048576 + 255) / 256, 256, 0, stream>>>(obs, OBSB, 1048576); // 65536*128/8
    f32_to_bf16_vec<<<(8192 + 255) / 256,  256, 0, stream>>>(W1,  W1b,  8192);
    f32_to_bf16_vec<<<(32768 + 255) / 256, 256, 0, stream>>>(W2,  W2b,  32768);
    f32_to_bf16_vec<<<(98304 + 255) / 256, 256, 0, stream>>>(Wih, Wihb, 98304);
    f32_to_bf16_vec<<<(98304 + 255) / 256, 256, 0, stream>>>(Whh, Whhb, 98304);

    // f1 = LN(relu(obs @ W1^T + b1))
    gemm_xwt<128, true><<<dim3(512, 4), 256, 0, stream>>>(OBSB, W1b, b1, X1, 512);
    ln_rows512<<<16384, 256, 0, stream>>>(X1, Y, g1, be1);
    // f2 = LN(relu(f1 @ W2^T + b2))
    gemm_xwt<512, true><<<dim3(512, 4), 256, 0, stream>>>(Y, W2b, b2, X1, 512);
    ln_rows512<<<16384, 256, 0, stream>>>(X1, Y, g2, be2);
    // gi = f2 @ Wih^T + bih
    gemm_xwt<512, false><<<dim3(512, 12), 256, 0, stream>>>(Y, Wihb, bih, GI, 1536);

    // GRU scan + fused output LN + hT
    float* out_p = (float*)d_out;
    float* hT_p  = out_p + (size_t)65536 * 512;
    gru_scan<<<32, 512, 0, stream>>>(GI, on_reset, hx, Whhb, bhh, gr, br, out_p, hT_p);
}